// Round 3
// baseline (639.794 us; speedup 1.0000x reference)
//
#include <hip/hip_runtime.h>
#include <math.h>

#define NB   256
#define ND   63
#define NN   3969        // 63*63

__device__ __forceinline__ float gelu_f(float v){
    return 0.5f * v * (1.0f + erff(v * 0.70710678118654752440f));
}

#define FMA4(A, W, S) { (A).x=fmaf((W).x,(S),(A).x); (A).y=fmaf((W).y,(S),(A).y); \
                        (A).z=fmaf((W).z,(S),(A).z); (A).w=fmaf((W).w,(S),(A).w); }

union F4  { float4 v;    float a[4];  };
union W16 { float4 v[4]; float a[16]; };
union W24 { float4 v[6]; float a[24]; };

__device__ __forceinline__ float4 gelu4(const F4& x){
    float4 r;
    r.x = gelu_f(x.a[0]); r.y = gelu_f(x.a[1]);
    r.z = gelu_f(x.a[2]); r.w = gelu_f(x.a[3]);
    return r;
}

// pair-base decode: units 0..H-1 are x-pairs (ox,ox+2), unit H is the singleton 2H.
__device__ __forceinline__ int dec_base(int uc, int H){
    int h2 = H >> 1;
    return (uc < h2) ? 4*uc : (uc < H) ? 4*(uc - h2) + 1 : 2*H;
}

// ---- 2x2-quad ConvTranspose stage: 4 same-tap-class pixels share each weight
// ---- read (weights amortized 4x), inputs read as float4 (stride-36 layout).
template<int SIN, int SOUT, int OST>
__device__ __forceinline__ void ct_quad_stage(const float* __restrict__ cin,
                                              float* __restrict__ cout,
                                              const float* __restrict__ wb,
                                              const float* __restrict__ bsv,
                                              int tid){
    const int H  = (SOUT - 1) >> 1;
    const int UX = H + 1;
    const int NU = UX * UX * 8;
    for (int u = tid; u < NU; u += 512){
        const int cell = u >> 3, q = u & 7;
        const int ucy = cell / UX, ucx = cell - ucy*UX;
        const int oy = dec_base(ucy, H), ox = dec_base(ucx, H);
        const bool vx = (ox + 2 <= 2*H), vy = (oy + 2 <= 2*H);
        int nky, kyA[2], iyA[2];
        if (oy & 1){ nky=2; kyA[0]=0; iyA[0]=(oy+1)>>1; kyA[1]=2; iyA[1]=(oy-1)>>1; }
        else       { nky=1; kyA[0]=1; iyA[0]=oy>>1; kyA[1]=1; iyA[1]=0; }
        int nkx, kxA[2], ixA[2];
        if (ox & 1){ nkx=2; kxA[0]=0; ixA[0]=(ox+1)>>1; kxA[1]=2; ixA[1]=(ox-1)>>1; }
        else       { nkx=1; kxA[0]=1; ixA[0]=ox>>1; kxA[1]=1; ixA[1]=0; }
        F4 a00, a01, a10, a11;
        a00.v = ((const float4*)bsv)[q]; a01.v = a00.v; a10.v = a00.v; a11.v = a00.v;
        for (int yi = 0; yi < nky; yi++)
        for (int xi = 0; xi < nkx; xi++){
            const float* wp  = wb + (kyA[yi]*3 + kxA[xi])*1024 + 4*q;
            const float* p00 = cin + (iyA[yi]*SIN + ixA[xi])*36;
            const float* p01 = p00 + 36;
            const float* p10 = p00 + SIN*36;
            const float* p11 = p10 + 36;
            #pragma unroll
            for (int g = 0; g < 8; g++){
                F4 i00, i01, i10, i11;
                i00.v = *(const float4*)(p00 + 4*g);
                i01.v = *(const float4*)(p01 + 4*g);
                i10.v = *(const float4*)(p10 + 4*g);
                i11.v = *(const float4*)(p11 + 4*g);
                #pragma unroll
                for (int cc = 0; cc < 4; cc++){
                    float4 w = *(const float4*)(wp + (4*g + cc)*32);
                    FMA4(a00.v, w, i00.a[cc]);
                    FMA4(a01.v, w, i01.a[cc]);
                    FMA4(a10.v, w, i10.a[cc]);
                    FMA4(a11.v, w, i11.a[cc]);
                }
            }
        }
        float4 g00 = gelu4(a00), g01 = gelu4(a01), g10 = gelu4(a10), g11 = gelu4(a11);
        size_t base = (size_t)(oy*SOUT + ox)*OST + 4*q;
        *(float4*)(cout + base) = g00;
        if (vx)        *(float4*)(cout + base + 2*(size_t)OST) = g01;
        if (vy)        *(float4*)(cout + base + 2*(size_t)SOUT*OST) = g10;
        if (vx && vy)  *(float4*)(cout + base + 2*(size_t)(SOUT+1)*OST) = g11;
    }
}

// ---- fused ct1..ct4 per sample; block 0 also writes the DFT tables to global.
__global__ __launch_bounds__(512) void k_ct1234(const float* __restrict__ kA,
                                                const float* __restrict__ cw1,
                                                const float* __restrict__ cw2,
                                                const float* __restrict__ cw3,
                                                const float* __restrict__ cw4,
                                                const float* __restrict__ b1,
                                                const float* __restrict__ b2,
                                                const float* __restrict__ b3,
                                                const float* __restrict__ b4,
                                                float* __restrict__ c4out,
                                                float* __restrict__ acc,
                                                float* __restrict__ Fgr,
                                                float* __restrict__ Fgi){
    __shared__ __align__(16) float wbuf[9216];   // [tap][ci][co32], reloaded per stage
    __shared__ __align__(16) float w1s[288];     // [tap][co32]
    __shared__ __align__(16) float c1s[31*36];   // [px][ci] stride 36 (+pad rows for masked reads)
    __shared__ __align__(16) float c2s[91*36];
    __shared__ __align__(16) float c3s[307*36];
    __shared__ float b1s[32], b2s[32], b3s[32], b4s[32];
    const int b = blockIdx.x, tid = threadIdx.x;
    if (b == 0 && tid == 0) acc[0] = 0.f;
    if (b == 0){
        // DFT tables to global (L1/L2-resident in k_solve): identical formula to k_solve's LDS copy
        for (int i = tid; i < 4096; i += 512){
            int r = i >> 6, c = i & 63;
            float vr = 0.f, vi = 0.f;
            if (r < 63 && c < 63){
                int m = (r * c) % 63;
                float ang = 6.283185307179586f * (float)m / 63.0f;
                vr = cosf(ang); vi = -sinf(ang);
            }
            Fgr[i] = vr; Fgi[i] = vi;
        }
    }
    for (int i = tid; i < 9216; i += 512){
        int ci = i / 288, co = (i / 9) & 31, tap = i % 9;
        wbuf[tap*1024 + ci*32 + co] = cw2[i];
    }
    if (tid < 288) w1s[(tid % 9)*32 + tid/9] = cw1[tid];
    if (tid < 32){ b1s[tid]=b1[tid]; b2s[tid]=b2[tid]; b3s[tid]=b3[tid]; b4s[tid]=b4[tid]; }
    __syncthreads();
    // ---- ct1: 3x3 -> 5x5, 1->32. 200 units ----
    if (tid < 200){
        int px = tid >> 3, q = tid & 7;
        int oy = px / 5, ox = px % 5;
        F4 a4; a4.v = ((const float4*)b1s)[q];
        int nky, kyA[2], iyA[2];
        if (oy & 1){ nky=2; kyA[0]=0; iyA[0]=(oy+1)/2; kyA[1]=2; iyA[1]=(oy-1)/2; }
        else       { nky=1; kyA[0]=1; iyA[0]=oy/2; kyA[1]=1; iyA[1]=0; }
        int nkx, kxA[2], ixA[2];
        if (ox & 1){ nkx=2; kxA[0]=0; ixA[0]=(ox+1)/2; kxA[1]=2; ixA[1]=(ox-1)/2; }
        else       { nkx=1; kxA[0]=1; ixA[0]=ox/2; kxA[1]=1; ixA[1]=0; }
        const float* ab = kA + b*9;
        for (int yi = 0; yi < nky; yi++)
        for (int xi = 0; xi < nkx; xi++){
            float v = ab[iyA[yi]*3 + ixA[xi]];
            float4 w = *(const float4*)(w1s + (kyA[yi]*3 + kxA[xi])*32 + 4*q);
            FMA4(a4.v, w, v);
        }
        *(float4*)(c1s + px*36 + 4*q) = gelu4(a4);
    }
    __syncthreads();
    ct_quad_stage<5, 9, 36>(c1s, c2s, wbuf, b2s, tid);       // ct2: 5->9
    __syncthreads();
    for (int i = tid; i < 9216; i += 512){
        int ci = i / 288, co = (i / 9) & 31, tap = i % 9;
        wbuf[tap*1024 + ci*32 + co] = cw3[i];
    }
    __syncthreads();
    ct_quad_stage<9, 17, 36>(c2s, c3s, wbuf, b3s, tid);      // ct3: 9->17
    __syncthreads();
    for (int i = tid; i < 9216; i += 512){
        int ci = i / 288, co = (i / 9) & 31, tap = i % 9;
        wbuf[tap*1024 + ci*32 + co] = cw4[i];
    }
    __syncthreads();
    // ct4: 17->33, channel-last to global
    ct_quad_stage<17, 33, 32>(c3s, c4out + (size_t)b*(1089*32), wbuf, b4s, tid);
}

// ---------------- mega solver, 512 threads, Hermitian-halved DFT -------------
// r13 regression root-cause: runtime-trip tail loop (t<nw) with nested loops in
// body -> acc2[] demoted to scratch (WRITE_SIZE 8KB->44MB). Fix: static unroll
// t=0..7, guard with px<63; boundary correction folded into the unrolled body.
__global__ __launch_bounds__(512) void k_solve(const float* __restrict__ x0g,
                                               const float* __restrict__ f,
                                               const float* __restrict__ kAg,
                                               const float* __restrict__ w1a, const float* __restrict__ b1a,
                                               const float* __restrict__ w2a, const float* __restrict__ b2a,
                                               const float* __restrict__ w1b, const float* __restrict__ b1b,
                                               const float* __restrict__ w2b, const float* __restrict__ b2b,
                                               const float* __restrict__ cw5,
                                               const float* __restrict__ b5,
                                               const float* __restrict__ fgr,
                                               const float* __restrict__ fgi,
                                               const float* __restrict__ c4g,
                                               float* __restrict__ accg){
    __shared__ __align__(16) float xs[63*68 + 8];    // row stride 68
    __shared__ __align__(16) float U[8576];          // c5s / rs_ext+ring / rP->MC | TtC->CC
    __shared__ __align__(16) float Fs_r[4096];       // F real (64x64), symmetric
    __shared__ __align__(16) float Fs_i[4096];       // F imag
    __shared__ __align__(16) float vcs[4096];        // v rows 0..31 interleaved (f4)
    __shared__ __align__(16) float Ks[208];          // composed 13x13 smoother kernel, stride 16
    __shared__ float ws5b[576];
    __shared__ float w1s[148], w2s[148], dvs[64], ds_r[32], ds_i[32], red[8], hs[100];
    const int b = blockIdx.x, tid = threadIdx.x;
    float* rs_ext = U;                // zero-extended residual: 75 rows x stride 76 (rows -6..68, cols -6..69)
    float* ring   = U + 5700;        // t~ on 3-wide outer frame: [3ch][792]
    float*  rP  = U;
    const float4* rP4 = (const float4*)U;
    float2* TtC = (float2*)(U + 4096);
    float2* MC2 = (float2*)U;
    float4* CC4 = (float4*)(U + 4096);
    float* c5s = U;
    const float4* F4r = (const float4*)Fs_r;
    const float4* F4i = (const float4*)Fs_i;
    const float4* Fg4r = (const float4*)fgr;
    const float4* Fg4i = (const float4*)fgi;
    const float4* vc4s = (const float4*)vcs;
    const float* fg = f + (size_t)b*NN;
    float ka[9];
    #pragma unroll
    for (int i = 0; i < 9; i++) ka[i] = kAg[b*9 + i];

    // ================= prologue =================
    for (int i = tid; i < 4096; i += 512){
        int r = i >> 6, c = i & 63;
        float vr = 0.f, vi = 0.f;
        if (r < 63 && c < 63){
            int m = (r * c) % 63;
            float ang = 6.283185307179586f * (float)m / 63.0f;
            vr = cosf(ang); vi = -sinf(ang);
        }
        Fs_r[i] = vr; Fs_i[i] = vi;
    }
    for (int i = tid; i < 576; i += 512){
        int ci = i / 18, co = (i / 9) & 1, tap = i % 9;
        ws5b[tap*64 + ci*2 + co] = cw5[i];
    }
    for (int i = tid; i < NN; i += 512) xs[(i/ND)*68 + (i%ND)] = x0g[(size_t)b*NN + i];
    // hypernet MLP (both stacks)
    if (tid < 100){
        float s = b1a[tid];
        #pragma unroll
        for (int i = 0; i < 9; i++) s = fmaf(ka[i], w1a[i*100 + tid], s);
        hs[tid] = gelu_f(s);
    }
    __syncthreads();
    if (tid < 147){
        float s = b2a[tid];
        for (int k = 0; k < 100; k++) s = fmaf(hs[k], w2a[k*147 + tid], s);
        w1s[tid] = s;
    }
    __syncthreads();
    if (tid < 100){
        float s = b1b[tid];
        #pragma unroll
        for (int i = 0; i < 9; i++) s = fmaf(ka[i], w1b[i*100 + tid], s);
        hs[tid] = gelu_f(s);
    }
    __syncthreads();
    if (tid < 147){
        float s = b2b[tid];
        for (int k = 0; k < 100; k++) s = fmaf(hs[k], w2b[k*147 + tid], s);
        w2s[tid] = s;
    }
    // ct5 from c4 -> c5s (in U)
    {
        const float* ib = c4g + (size_t)b * (1089*32);
        float bb0 = b5[0], bb1 = b5[1];
        for (int p = tid; p < NN; p += 512){
            int oy = p / ND, ox = p % ND;
            float a0 = bb0, a1 = bb1;
            int nky, kyA[2], iyA[2];
            if ((oy & 1) == 0){ nky=2; kyA[0]=0; iyA[0]=oy/2+1; kyA[1]=2; iyA[1]=oy/2; }
            else              { nky=1; kyA[0]=1; iyA[0]=(oy+1)/2; kyA[1]=1; iyA[1]=0; }
            int nkx, kxA[2], ixA[2];
            if ((ox & 1) == 0){ nkx=2; kxA[0]=0; ixA[0]=ox/2+1; kxA[1]=2; ixA[1]=ox/2; }
            else              { nkx=1; kxA[0]=1; ixA[0]=(ox+1)/2; kxA[1]=1; ixA[1]=0; }
            for (int yi = 0; yi < nky; yi++)
            for (int xi = 0; xi < nkx; xi++){
                const float* ip = ib + ((size_t)iyA[yi]*33 + ixA[xi])*32;
                const float* wp = ws5b + (kyA[yi]*3 + kxA[xi])*64;
                #pragma unroll
                for (int g = 0; g < 8; g++){
                    F4 iv; iv.v = *(const float4*)(ip + 4*g);
                    #pragma unroll
                    for (int q = 0; q < 4; q++){
                        int ci = 4*g + q;
                        a0 = fmaf(iv.a[q], wp[ci*2],   a0);
                        a1 = fmaf(iv.a[q], wp[ci*2+1], a1);
                    }
                }
            }
            c5s[p]      = a0;
            c5s[NN + p] = a1;
        }
    }
    __syncthreads();
    // build vcs + dvs; also the composed smoother kernel K (once, w1/w2 are iter-invariant)
    {
        const float sc = 1.0f / 3969.0f;
        float4* vout = (float4*)vcs;
        for (int i = tid; i < 1024; i += 512){
            int ky = i >> 5, ct2 = i & 31;
            float4 o;
            #pragma unroll
            for (int j = 0; j < 2; j++){
                int kx = 2*ct2 + j;
                float re = 0.f, im = 0.f;
                if (kx <= 31){ int o2 = 2*(ky*ND + kx); re = c5s[o2]*sc; im = c5s[o2+1]*sc; }
                else if (kx <= 62){
                    int sy = (ND - ky) % ND, sx = ND - kx;
                    int o2 = 2*(sy*ND + sx); re = c5s[o2]*sc; im = -c5s[o2+1]*sc;
                }
                if (j == 0){ o.x = re; o.y = im; } else { o.z = re; o.w = im; }
            }
            vout[i] = o;
        }
        if (tid < 32){
            float2 d = {0.f, 0.f};
            if (tid >= 1){
                int iA = (ND - tid) * ND, iB = tid * ND;
                d.x = (c5s[2*iA]     - c5s[2*iB])     * sc;
                d.y = (c5s[2*iA + 1] + c5s[2*iB + 1]) * sc;
            }
            ((float2*)dvs)[tid] = d;
        }
        if (tid < 169){
            int dy = tid / 13, dx = tid - 13*dy;
            float s = 0.f;
            for (int c = 0; c < 3; c++){
                int ay0 = dy > 6 ? dy - 6 : 0, ay1 = dy < 6 ? dy : 6;
                int ax0 = dx > 6 ? dx - 6 : 0, ax1 = dx < 6 ? dx : 6;
                for (int ay = ay0; ay <= ay1; ay++)
                for (int ax = ax0; ax <= ax1; ax++)
                    s = fmaf(w1s[c*49 + ay*7 + ax], w2s[c*49 + (dy-ay)*7 + (dx-ax)], s);
            }
            Ks[dy*16 + dx] = s;
        }
    }
    __syncthreads();

    const int kt = tid >> 4, cg = tid & 15;

    for (int it = 0; it < 5; it++){
        // ---- zero union (provides rs_ext zero borders + ring init) ----
        { float4 z = {0.f,0.f,0.f,0.f}; float4* U4 = (float4*)U;
          for (int i = tid; i < 2144; i += 512) U4[i] = z; }
        __syncthreads();
        // ---- residual -> rs_ext (row y at (y+6), col xx at (xx+6), stride 76) ----
        for (int i = tid; i < NN; i += 512){
            int y = i / ND, xx = i % ND;
            float s = 0.f;
            #pragma unroll
            for (int dy = 0; dy < 3; dy++){
                int u = y + dy;
                #pragma unroll
                for (int dx = 0; dx < 3; dx++){
                    int v = xx + dx;
                    float p;
                    if (u == 64 || v == 64)    p = 1.0f;
                    else if (u == 0 || v == 0) p = 0.0f;
                    else                       p = xs[(u-1)*68 + (v-1)];
                    s = fmaf(p, ka[dy*3 + dx], s);
                }
            }
            rs_ext[(y+6)*76 + xx + 6] = fg[i] - s;
        }
        __syncthreads();
        // ---- smoother: one 13x13 composed conv (+ ring t~ for boundary fix) ----
        const bool act = tid < 504;
        const int y0 = tid >> 3, x0c = 8*(tid & 7);
        float acc2[8] = {};
        if (act){
            for (int dy = 0; dy < 13; dy++){
                const float4* rp = (const float4*)(rs_ext + (y0 + dy)*76 + x0c);
                W24 w;
                #pragma unroll
                for (int k = 0; k < 6; k++) w.v[k] = rp[k];
                W16 kr;
                const float4* kp = (const float4*)(Ks + dy*16);
                kr.v[0]=kp[0]; kr.v[1]=kp[1]; kr.v[2]=kp[2]; kr.v[3]=kp[3];
                #pragma unroll
                for (int dx = 0; dx < 13; dx++){
                    float wv = kr.a[dx];
                    #pragma unroll
                    for (int t = 0; t < 8; t++) acc2[t] = fmaf(wv, w.a[t+dx], acc2[t]);
                }
            }
        }
        // ring t~: conv1 values on the 3-wide frame outside the domain (per channel)
        for (int j5 = tid; j5 < 2376; j5 += 512){
            int c = 0, j = j5;
            if (j >= 1584){ c = 2; j -= 1584; }
            else if (j >= 792){ c = 1; j -= 792; }
            int qy, qx;
            if (j < 207)      { qy = -3 + j/69;        qx = -3 + j%69; }
            else if (j < 414) { int t2 = j-207; qy = 63 + t2/69; qx = -3 + t2%69; }
            else if (j < 603) { int t2 = j-414; qy = t2/3;       qx = -3 + t2%3; }
            else              { int t2 = j-603; qy = t2/3;       qx = 63 + t2%3; }
            const float* wc = w1s + c*49;
            float s = 0.f;
            for (int ay = 0; ay < 7; ay++){
                const float* rp = rs_ext + (qy + ay + 3)*76 + (qx + 3);
                #pragma unroll
                for (int ax = 0; ax < 7; ax++) s = fmaf(wc[ay*7 + ax], rp[ax], s);
            }
            ring[c*792 + j] = s;
        }
        __syncthreads();
        // ---- boundary correction + x update: STATIC unroll, all acc2 indices
        // ---- compile-time (r13 spill fix) ----
        if (act){
            const bool rowb = (y0 < 3) | (y0 > 59);
            #pragma unroll
            for (int t = 0; t < 8; t++){
                const int px = x0c + t;
                const bool valid = px < 63;
                if (valid & (rowb | (px < 3) | (px > 59))){
                    float corr = 0.f;
                    for (int by = 0; by < 7; by++){
                        int qy = y0 + by - 3;
                        bool yin = (qy >= 0) & (qy < 63);
                        for (int bx = 0; bx < 7; bx++){
                            int qx = px + bx - 3;
                            if (yin && qx >= 0 && qx < 63) continue;
                            int rj;
                            if      (qy < 0)   rj = (qy+3)*69 + (qx+3);
                            else if (qy >= 63) rj = 207 + (qy-63)*69 + (qx+3);
                            else if (qx < 0)   rj = 414 + qy*3 + (qx+3);
                            else               rj = 603 + qy*3 + (qx-63);
                            int bo = by*7 + bx;
                            corr = fmaf(w2s[bo],      ring[rj],         corr);
                            corr = fmaf(w2s[49+bo],   ring[792+rj],     corr);
                            corr = fmaf(w2s[98+bo],   ring[1584+rj],    corr);
                        }
                    }
                    acc2[t] -= corr;
                }
                if (valid) xs[y0*68 + px] += acc2[t];
            }
        }
        __syncthreads();
        // ---- residual of updated x -> rP ----
        for (int i = tid; i < 4096; i += 512){
            int y = i >> 6, xx = i & 63;
            float val = 0.f;
            if (y < 63 && xx < 63){
                float s = 0.f;
                #pragma unroll
                for (int dy = 0; dy < 3; dy++){
                    int u = y + dy;
                    #pragma unroll
                    for (int dx = 0; dx < 3; dx++){
                        int v = xx + dx;
                        float p;
                        if (u == 64 || v == 64)    p = 1.0f;
                        else if (u == 0 || v == 0) p = 0.0f;
                        else                       p = xs[(u-1)*68 + (v-1)];
                        s = fmaf(p, ka[dy*3 + dx], s);
                    }
                }
                val = fg[y*ND + xx] - s;
            }
            rP[i] = val;
        }
        __syncthreads();
        // ---- Phase A (F symmetric: row-kt float4 quads; m=63 terms are zero) ----
        {
            float tr0=0.f,ti0=0.f,tr1=0.f,ti1=0.f,tr2=0.f,ti2=0.f,tr3=0.f,ti3=0.f;
            for (int mq = 0; mq < 16; mq++){
                F4 f4r, f4i;
                f4r.v = F4r[kt*16 + mq];
                f4i.v = F4i[kt*16 + mq];
                #pragma unroll
                for (int j = 0; j < 4; j++){
                    F4 rv; rv.v = rP4[(4*mq + j)*16 + cg];
                    float fr = f4r.a[j], fi = f4i.a[j];
                    tr0 = fmaf(fr, rv.a[0], tr0); ti0 = fmaf(fi, rv.a[0], ti0);
                    tr1 = fmaf(fr, rv.a[1], tr1); ti1 = fmaf(fi, rv.a[1], ti1);
                    tr2 = fmaf(fr, rv.a[2], tr2); ti2 = fmaf(fi, rv.a[2], ti2);
                    tr3 = fmaf(fr, rv.a[3], tr3); ti3 = fmaf(fi, rv.a[3], ti3);
                }
            }
            const int c0 = 4*cg;
            TtC[(c0+0)*32 + ((kt + c0 + 0) & 31)] = make_float2(tr0, ti0);
            TtC[(c0+1)*32 + ((kt + c0 + 1) & 31)] = make_float2(tr1, ti1);
            TtC[(c0+2)*32 + ((kt + c0 + 2) & 31)] = make_float2(tr2, ti2);
            TtC[(c0+3)*32 + ((kt + c0 + 3) & 31)] = make_float2(tr3, ti3);
        }
        __syncthreads();
        // ---- Phase B (F from global/L1 — off the LDS pipe) ----
        {
            float R0r=0.f,R0i=0.f,R1r=0.f,R1i=0.f,R2r=0.f,R2i=0.f,R3r=0.f,R3i=0.f;
            #pragma unroll 3
            for (int n = 0; n < 63; n++){
                float2 T = TtC[n*32 + ((kt + n) & 31)];
                F4 fr, fi;
                fr.v = Fg4r[n*16 + cg];
                fi.v = Fg4i[n*16 + cg];
                R0r = fmaf(T.x, fr.a[0], R0r); R0r = fmaf(-T.y, fi.a[0], R0r);
                R0i = fmaf(T.x, fi.a[0], R0i); R0i = fmaf( T.y, fr.a[0], R0i);
                R1r = fmaf(T.x, fr.a[1], R1r); R1r = fmaf(-T.y, fi.a[1], R1r);
                R1i = fmaf(T.x, fi.a[1], R1i); R1i = fmaf( T.y, fr.a[1], R1i);
                R2r = fmaf(T.x, fr.a[2], R2r); R2r = fmaf(-T.y, fi.a[2], R2r);
                R2i = fmaf(T.x, fi.a[2], R2i); R2i = fmaf( T.y, fr.a[2], R2i);
                R3r = fmaf(T.x, fr.a[3], R3r); R3r = fmaf(-T.y, fi.a[3], R3r);
                R3i = fmaf(T.x, fi.a[3], R3i); R3i = fmaf( T.y, fr.a[3], R3i);
            }
            if (cg == 0){
                float2 dv = ((const float2*)dvs)[kt];
                ds_r[kt] = R0r*dv.x + R0i*dv.y;
                ds_i[kt] = R0r*dv.y - R0i*dv.x;
            }
            float4 vA = vc4s[kt*32 + 2*cg];
            float4 vB = vc4s[kt*32 + 2*cg + 1];
            const int c0 = 4*cg, rot = kt;
            MC2[kt*64 + ((c0+0 + rot) & 63)] = make_float2(R0r*vA.x - R0i*vA.y, R0r*vA.y + R0i*vA.x);
            MC2[kt*64 + ((c0+1 + rot) & 63)] = make_float2(R1r*vA.z - R1i*vA.w, R1r*vA.w + R1i*vA.z);
            MC2[kt*64 + ((c0+2 + rot) & 63)] = make_float2(R2r*vB.x - R2i*vB.y, R2r*vB.y + R2i*vB.x);
            MC2[kt*64 + ((c0+3 + rot) & 63)] = make_float2(R3r*vB.z - R3i*vB.w, R3r*vB.w + R3i*vB.z);
        }
        __syncthreads();
        // ---- Phase D (F from global/L1) ----
        {
            float C0r=0.f,C0i=0.f,C1r=0.f,C1i=0.f,C2r=0.f,C2i=0.f,C3r=0.f,C3i=0.f;
            const int rot = kt;
            #pragma unroll 3
            for (int l = 0; l < 63; l++){
                float2 Mv = MC2[kt*64 + ((l + rot) & 63)];
                F4 fr, fi;
                fr.v = Fg4r[l*16 + cg];
                fi.v = Fg4i[l*16 + cg];
                C0r = fmaf(Mv.x, fr.a[0], C0r); C0r = fmaf( Mv.y, fi.a[0], C0r);
                C0i = fmaf(Mv.y, fr.a[0], C0i); C0i = fmaf(-Mv.x, fi.a[0], C0i);
                C1r = fmaf(Mv.x, fr.a[1], C1r); C1r = fmaf( Mv.y, fi.a[1], C1r);
                C1i = fmaf(Mv.y, fr.a[1], C1i); C1i = fmaf(-Mv.x, fi.a[1], C1i);
                C2r = fmaf(Mv.x, fr.a[2], C2r); C2r = fmaf( Mv.y, fi.a[2], C2r);
                C2i = fmaf(Mv.y, fr.a[2], C2i); C2i = fmaf(-Mv.x, fi.a[2], C2i);
                C3r = fmaf(Mv.x, fr.a[3], C3r); C3r = fmaf( Mv.y, fi.a[3], C3r);
                C3i = fmaf(Mv.y, fr.a[3], C3i); C3i = fmaf(-Mv.x, fi.a[3], C3i);
            }
            float sc2 = (kt == 0) ? 0.5f : 1.0f;
            CC4[kt*33 + 2*cg]     = make_float4(C0r*sc2, C0i*sc2, C1r*sc2, C1i*sc2);
            CC4[kt*33 + 2*cg + 1] = make_float4(C2r*sc2, C2i*sc2, C3r*sc2, C3i*sc2);
        }
        __syncthreads();
        // ---- Phase E: mirror-row pairing (rows pr and 63-pr share F magnitudes) ----
        if (tid < 256){
            const int pr = tid >> 3, qb = tid & 7;
            float sr[8] = {}, si[8] = {};
            float er = 0.f, ei = 0.f;
            for (int nq = 0; nq < 8; nq++){
                F4 f4r, f4i;
                f4r.v = F4r[pr*16 + nq];
                f4i.v = F4i[pr*16 + nq];
                #pragma unroll
                for (int j = 0; j < 4; j++){
                    int n = 4*nq + j;
                    float fr = f4r.a[j], fi = f4i.a[j];
                    float4 cA = CC4[n*33 + qb];
                    float4 cB = CC4[n*33 + qb + 8];
                    float4 cC = CC4[n*33 + qb + 16];
                    float4 cD = CC4[n*33 + qb + 24];
                    sr[0]=fmaf(fr,cA.x,sr[0]); si[0]=fmaf(fi,cA.y,si[0]);
                    sr[1]=fmaf(fr,cA.z,sr[1]); si[1]=fmaf(fi,cA.w,si[1]);
                    sr[2]=fmaf(fr,cB.x,sr[2]); si[2]=fmaf(fi,cB.y,si[2]);
                    sr[3]=fmaf(fr,cB.z,sr[3]); si[3]=fmaf(fi,cB.w,si[3]);
                    sr[4]=fmaf(fr,cC.x,sr[4]); si[4]=fmaf(fi,cC.y,si[4]);
                    sr[5]=fmaf(fr,cC.z,sr[5]); si[5]=fmaf(fi,cC.w,si[5]);
                    sr[6]=fmaf(fr,cD.x,sr[6]); si[6]=fmaf(fi,cD.y,si[6]);
                    sr[7]=fmaf(fr,cD.z,sr[7]); si[7]=fmaf(fi,cD.w,si[7]);
                    er = fmaf(fr, ds_r[n], er); ei = fmaf(fi, ds_i[n], ei);
                }
            }
            {   // row pr: y = sr+si, e = er-ei
                float e0 = er - ei;
                float* xrow = xs + pr*68;
                float2* xp0 = (float2*)(xrow + 2*qb);
                float2* xp1 = (float2*)(xrow + 2*qb + 16);
                float2* xp2 = (float2*)(xrow + 2*qb + 32);
                float2* xp3 = (float2*)(xrow + 2*qb + 48);
                float2 v0=*xp0, v1=*xp1, v2=*xp2, v3=*xp3;
                v0.x += 2.f*(sr[0]+si[0]) + e0; v0.y += 2.f*(sr[1]+si[1]) + e0;
                v1.x += 2.f*(sr[2]+si[2]) + e0; v1.y += 2.f*(sr[3]+si[3]) + e0;
                v2.x += 2.f*(sr[4]+si[4]) + e0; v2.y += 2.f*(sr[5]+si[5]) + e0;
                v3.x += 2.f*(sr[6]+si[6]) + e0; v3.y += 2.f*(sr[7]+si[7]) + e0;
                *xp0=v0; *xp1=v1; *xp2=v2; *xp3=v3;
            }
            if (pr > 0){ // row 63-pr: fi -> -fi  =>  y = sr-si, e = er+ei
                float e1 = er + ei;
                float* xrow = xs + (63-pr)*68;
                float2* xp0 = (float2*)(xrow + 2*qb);
                float2* xp1 = (float2*)(xrow + 2*qb + 16);
                float2* xp2 = (float2*)(xrow + 2*qb + 32);
                float2* xp3 = (float2*)(xrow + 2*qb + 48);
                float2 v0=*xp0, v1=*xp1, v2=*xp2, v3=*xp3;
                v0.x += 2.f*(sr[0]-si[0]) + e1; v0.y += 2.f*(sr[1]-si[1]) + e1;
                v1.x += 2.f*(sr[2]-si[2]) + e1; v1.y += 2.f*(sr[3]-si[3]) + e1;
                v2.x += 2.f*(sr[4]-si[4]) + e1; v2.y += 2.f*(sr[5]-si[5]) + e1;
                v3.x += 2.f*(sr[6]-si[6]) + e1; v3.y += 2.f*(sr[7]-si[7]) + e1;
                *xp0=v0; *xp1=v1; *xp2=v2; *xp3=v3;
            }
        }
        __syncthreads();
    }
    // ---- final residual + norm ----
    float s = 0.f;
    for (int i = tid; i < NN; i += 512){
        int y = i / ND, xx = i % ND;
        float cv = 0.f;
        #pragma unroll
        for (int dy = 0; dy < 3; dy++){
            int u = y + dy;
            #pragma unroll
            for (int dx = 0; dx < 3; dx++){
                int v = xx + dx;
                float p;
                if (u == 64 || v == 64)    p = 1.0f;
                else if (u == 0 || v == 0) p = 0.0f;
                else                       p = xs[(u-1)*68 + (v-1)];
                cv = fmaf(p, ka[dy*3 + dx], cv);
            }
        }
        float r = fg[i] - cv;
        s = fmaf(r, r, s);
    }
    #pragma unroll
    for (int off = 32; off > 0; off >>= 1) s += __shfl_down(s, off, 64);
    int lane = tid & 63, w = tid >> 6;
    if (lane == 0) red[w] = s;
    __syncthreads();
    if (tid == 0){
        float t = 0.f;
        #pragma unroll
        for (int i = 0; i < 8; i++) t += red[i];
        atomicAdd(accg, t);
    }
}

__global__ void k_final(const float* __restrict__ acc, float* __restrict__ out){
    if (threadIdx.x == 0 && blockIdx.x == 0) out[0] = sqrtf(acc[0]) * (1.0f/256.0f);
}

// ---------------- host ------------------------------------------------------
extern "C" void kernel_launch(void* const* d_in, const int* in_sizes, int n_in,
                              void* d_out, int out_size, void* d_ws, size_t ws_size,
                              hipStream_t stream){
    const float* x0     = (const float*)d_in[0];
    const float* f      = (const float*)d_in[1];
    const float* kA     = (const float*)d_in[2];
    const float* fc1_w1 = (const float*)d_in[3];
    const float* fc1_b1 = (const float*)d_in[4];
    const float* fc1_w2 = (const float*)d_in[5];
    const float* fc1_b2 = (const float*)d_in[6];
    const float* fc2_w1 = (const float*)d_in[7];
    const float* fc2_b1 = (const float*)d_in[8];
    const float* fc2_w2 = (const float*)d_in[9];
    const float* fc2_b2 = (const float*)d_in[10];
    const float* ct1_w  = (const float*)d_in[11];
    const float* ct1_b  = (const float*)d_in[12];
    const float* ct2_w  = (const float*)d_in[13];
    const float* ct2_b  = (const float*)d_in[14];
    const float* ct3_w  = (const float*)d_in[15];
    const float* ct3_b  = (const float*)d_in[16];
    const float* ct4_w  = (const float*)d_in[17];
    const float* ct4_b  = (const float*)d_in[18];
    const float* ct5_w  = (const float*)d_in[19];
    const float* ct5_b  = (const float*)d_in[20];
    float* out = (float*)d_out;

    float* ws = (float*)d_ws;
    size_t off = 0;
    auto take = [&](size_t n){ float* p = ws + off; off += (n + 63) & ~(size_t)63; return p; };
    float* acc = take(64);
    float* Fr  = take(4096);
    float* Fi  = take(4096);
    float* c4  = take((size_t)NB*32*1089);
    (void)ws_size; (void)in_sizes; (void)n_in; (void)out_size;

    k_ct1234<<<NB, 512, 0, stream>>>(kA, ct1_w, ct2_w, ct3_w, ct4_w,
                                     ct1_b, ct2_b, ct3_b, ct4_b, c4, acc, Fr, Fi);
    k_solve<<<NB, 512, 0, stream>>>(x0, f, kA,
                                    fc1_w1, fc1_b1, fc1_w2, fc1_b2,
                                    fc2_w1, fc2_b1, fc2_w2, fc2_b2,
                                    ct5_w, ct5_b, Fr, Fi, c4, acc);
    k_final<<<1, 64, 0, stream>>>(acc, out);
}

// Round 4
// 454.786 us; speedup vs baseline: 1.4068x; 1.4068x over previous
//
#include <hip/hip_runtime.h>
#include <math.h>

#define NB   256
#define ND   63
#define NN   3969        // 63*63

__device__ __forceinline__ float gelu_f(float v){
    return 0.5f * v * (1.0f + erff(v * 0.70710678118654752440f));
}

#define FMA4(A, W, S) { (A).x=fmaf((W).x,(S),(A).x); (A).y=fmaf((W).y,(S),(A).y); \
                        (A).z=fmaf((W).z,(S),(A).z); (A).w=fmaf((W).w,(S),(A).w); }

union F4  { float4 v;    float a[4];  };
union W16 { float4 v[4]; float a[16]; };

__device__ __forceinline__ float4 gelu4(const F4& x){
    float4 r;
    r.x = gelu_f(x.a[0]); r.y = gelu_f(x.a[1]);
    r.z = gelu_f(x.a[2]); r.w = gelu_f(x.a[3]);
    return r;
}

// pair-base decode: units 0..H-1 are x-pairs (ox,ox+2), unit H is the singleton 2H.
__device__ __forceinline__ int dec_base(int uc, int H){
    int h2 = H >> 1;
    return (uc < h2) ? 4*uc : (uc < H) ? 4*(uc - h2) + 1 : 2*H;
}

// ---- 2x2-quad ConvTranspose stage: 4 same-tap-class pixels share each weight
// ---- read (weights amortized 4x), inputs read as float4 (stride-36 layout).
template<int SIN, int SOUT, int OST>
__device__ __forceinline__ void ct_quad_stage(const float* __restrict__ cin,
                                              float* __restrict__ cout,
                                              const float* __restrict__ wb,
                                              const float* __restrict__ bsv,
                                              int tid){
    const int H  = (SOUT - 1) >> 1;
    const int UX = H + 1;
    const int NU = UX * UX * 8;
    for (int u = tid; u < NU; u += 512){
        const int cell = u >> 3, q = u & 7;
        const int ucy = cell / UX, ucx = cell - ucy*UX;
        const int oy = dec_base(ucy, H), ox = dec_base(ucx, H);
        const bool vx = (ox + 2 <= 2*H), vy = (oy + 2 <= 2*H);
        int nky, kyA[2], iyA[2];
        if (oy & 1){ nky=2; kyA[0]=0; iyA[0]=(oy+1)>>1; kyA[1]=2; iyA[1]=(oy-1)>>1; }
        else       { nky=1; kyA[0]=1; iyA[0]=oy>>1; kyA[1]=1; iyA[1]=0; }
        int nkx, kxA[2], ixA[2];
        if (ox & 1){ nkx=2; kxA[0]=0; ixA[0]=(ox+1)>>1; kxA[1]=2; ixA[1]=(ox-1)>>1; }
        else       { nkx=1; kxA[0]=1; ixA[0]=ox>>1; kxA[1]=1; ixA[1]=0; }
        F4 a00, a01, a10, a11;
        a00.v = ((const float4*)bsv)[q]; a01.v = a00.v; a10.v = a00.v; a11.v = a00.v;
        for (int yi = 0; yi < nky; yi++)
        for (int xi = 0; xi < nkx; xi++){
            const float* wp  = wb + (kyA[yi]*3 + kxA[xi])*1024 + 4*q;
            const float* p00 = cin + (iyA[yi]*SIN + ixA[xi])*36;
            const float* p01 = p00 + 36;
            const float* p10 = p00 + SIN*36;
            const float* p11 = p10 + 36;
            #pragma unroll
            for (int g = 0; g < 8; g++){
                F4 i00, i01, i10, i11;
                i00.v = *(const float4*)(p00 + 4*g);
                i01.v = *(const float4*)(p01 + 4*g);
                i10.v = *(const float4*)(p10 + 4*g);
                i11.v = *(const float4*)(p11 + 4*g);
                #pragma unroll
                for (int cc = 0; cc < 4; cc++){
                    float4 w = *(const float4*)(wp + (4*g + cc)*32);
                    FMA4(a00.v, w, i00.a[cc]);
                    FMA4(a01.v, w, i01.a[cc]);
                    FMA4(a10.v, w, i10.a[cc]);
                    FMA4(a11.v, w, i11.a[cc]);
                }
            }
        }
        float4 g00 = gelu4(a00), g01 = gelu4(a01), g10 = gelu4(a10), g11 = gelu4(a11);
        size_t base = (size_t)(oy*SOUT + ox)*OST + 4*q;
        *(float4*)(cout + base) = g00;
        if (vx)        *(float4*)(cout + base + 2*(size_t)OST) = g01;
        if (vy)        *(float4*)(cout + base + 2*(size_t)SOUT*OST) = g10;
        if (vx && vy)  *(float4*)(cout + base + 2*(size_t)(SOUT+1)*OST) = g11;
    }
}

// ---- fused ct1..ct4 per sample; block 0 also writes the DFT tables to global.
__global__ __launch_bounds__(512) void k_ct1234(const float* __restrict__ kA,
                                                const float* __restrict__ cw1,
                                                const float* __restrict__ cw2,
                                                const float* __restrict__ cw3,
                                                const float* __restrict__ cw4,
                                                const float* __restrict__ b1,
                                                const float* __restrict__ b2,
                                                const float* __restrict__ b3,
                                                const float* __restrict__ b4,
                                                float* __restrict__ c4out,
                                                float* __restrict__ acc,
                                                float* __restrict__ Fgr,
                                                float* __restrict__ Fgi){
    __shared__ __align__(16) float wbuf[9216];   // [tap][ci][co32], reloaded per stage
    __shared__ __align__(16) float w1s[288];     // [tap][co32]
    __shared__ __align__(16) float c1s[31*36];   // [px][ci] stride 36 (+pad rows for masked reads)
    __shared__ __align__(16) float c2s[91*36];
    __shared__ __align__(16) float c3s[307*36];
    __shared__ float b1s[32], b2s[32], b3s[32], b4s[32];
    const int b = blockIdx.x, tid = threadIdx.x;
    if (b == 0 && tid == 0) acc[0] = 0.f;
    if (b == 0){
        // DFT tables to global (L1/L2-resident in k_solve)
        for (int i = tid; i < 4096; i += 512){
            int r = i >> 6, c = i & 63;
            float vr = 0.f, vi = 0.f;
            if (r < 63 && c < 63){
                int m = (r * c) % 63;
                float ang = 6.283185307179586f * (float)m / 63.0f;
                vr = cosf(ang); vi = -sinf(ang);
            }
            Fgr[i] = vr; Fgi[i] = vi;
        }
    }
    for (int i = tid; i < 9216; i += 512){
        int ci = i / 288, co = (i / 9) & 31, tap = i % 9;
        wbuf[tap*1024 + ci*32 + co] = cw2[i];
    }
    if (tid < 288) w1s[(tid % 9)*32 + tid/9] = cw1[tid];
    if (tid < 32){ b1s[tid]=b1[tid]; b2s[tid]=b2[tid]; b3s[tid]=b3[tid]; b4s[tid]=b4[tid]; }
    __syncthreads();
    // ---- ct1: 3x3 -> 5x5, 1->32. 200 units ----
    if (tid < 200){
        int px = tid >> 3, q = tid & 7;
        int oy = px / 5, ox = px % 5;
        F4 a4; a4.v = ((const float4*)b1s)[q];
        int nky, kyA[2], iyA[2];
        if (oy & 1){ nky=2; kyA[0]=0; iyA[0]=(oy+1)/2; kyA[1]=2; iyA[1]=(oy-1)/2; }
        else       { nky=1; kyA[0]=1; iyA[0]=oy/2; kyA[1]=1; iyA[1]=0; }
        int nkx, kxA[2], ixA[2];
        if (ox & 1){ nkx=2; kxA[0]=0; ixA[0]=(ox+1)/2; kxA[1]=2; ixA[1]=(ox-1)/2; }
        else       { nkx=1; kxA[0]=1; ixA[0]=ox/2; kxA[1]=1; ixA[1]=0; }
        const float* ab = kA + b*9;
        for (int yi = 0; yi < nky; yi++)
        for (int xi = 0; xi < nkx; xi++){
            float v = ab[iyA[yi]*3 + ixA[xi]];
            float4 w = *(const float4*)(w1s + (kyA[yi]*3 + kxA[xi])*32 + 4*q);
            FMA4(a4.v, w, v);
        }
        *(float4*)(c1s + px*36 + 4*q) = gelu4(a4);
    }
    __syncthreads();
    ct_quad_stage<5, 9, 36>(c1s, c2s, wbuf, b2s, tid);       // ct2: 5->9
    __syncthreads();
    for (int i = tid; i < 9216; i += 512){
        int ci = i / 288, co = (i / 9) & 31, tap = i % 9;
        wbuf[tap*1024 + ci*32 + co] = cw3[i];
    }
    __syncthreads();
    ct_quad_stage<9, 17, 36>(c2s, c3s, wbuf, b3s, tid);      // ct3: 9->17
    __syncthreads();
    for (int i = tid; i < 9216; i += 512){
        int ci = i / 288, co = (i / 9) & 31, tap = i % 9;
        wbuf[tap*1024 + ci*32 + co] = cw4[i];
    }
    __syncthreads();
    // ct4: 17->33, channel-last to global
    ct_quad_stage<17, 33, 32>(c3s, c4out + (size_t)b*(1089*32), wbuf, b4s, tid);
}

// ---------------- mega solver, 512 threads, Hermitian-halved DFT -------------
// Structure = r0's proven kernel (281us, 88 VGPR, no spill). Changes vs r0:
//  * Fs_r/Fs_i LDS tables REMOVED (-32KB LDS, -8 cos/sin per thread): all F
//    reads come from global fgr/fgi (L1-resident, VMEM pipe, off the LDS pipe).
//  * Phase A: F via float4 symmetry quads (F[m][k]=F[k][m]).
//  * Phase E: mirror-row pairing (rows pr / 63-pr share F magnitudes) halves
//    the CC4 LDS re-reads. All three verified absmax=0.0 in r1/r3.
// Smoother stays the r0 two-pass 7x7 (the composed-13x13 variant spilled:
// WRITE_SIZE 8KB->49MB in r1/r3).
__global__ __launch_bounds__(512) void k_solve(const float* __restrict__ x0g,
                                               const float* __restrict__ f,
                                               const float* __restrict__ kAg,
                                               const float* __restrict__ w1a, const float* __restrict__ b1a,
                                               const float* __restrict__ w2a, const float* __restrict__ b2a,
                                               const float* __restrict__ w1b, const float* __restrict__ b1b,
                                               const float* __restrict__ w2b, const float* __restrict__ b2b,
                                               const float* __restrict__ cw5,
                                               const float* __restrict__ b5,
                                               const float* __restrict__ fgr,
                                               const float* __restrict__ fgi,
                                               const float* __restrict__ c4g,
                                               float* __restrict__ accg){
    __shared__ __align__(16) float xs[63*68 + 8];    // row stride 68
    __shared__ __align__(16) float U[8576];          // c5s / rs|tc / rP->MC | TtC->CC
    __shared__ __align__(16) float vcs[4096];        // v rows 0..31 interleaved (f4)
    __shared__ float ws5b[576];
    __shared__ float w1s[148], w2s[148], dvs[64], ds_r[32], ds_i[32], red[8], hs[100];
    const int b = blockIdx.x, tid = threadIdx.x;
    float* rs = U;
    float* tc = U + 4288;
    float*  rP  = U;
    const float4* rP4 = (const float4*)U;
    float2* TtC = (float2*)(U + 4096);
    float2* MC2 = (float2*)U;
    float4* CC4 = (float4*)(U + 4096);
    float* c5s = U;
    const float4* Fg4r = (const float4*)fgr;
    const float4* Fg4i = (const float4*)fgi;
    const float4* vc4s = (const float4*)vcs;
    const float* fg = f + (size_t)b*NN;
    float ka[9];
    #pragma unroll
    for (int i = 0; i < 9; i++) ka[i] = kAg[b*9 + i];

    // ================= prologue =================
    for (int i = tid; i < 576; i += 512){
        int ci = i / 18, co = (i / 9) & 1, tap = i % 9;
        ws5b[tap*64 + ci*2 + co] = cw5[i];
    }
    for (int i = tid; i < NN; i += 512) xs[(i/ND)*68 + (i%ND)] = x0g[(size_t)b*NN + i];
    // hypernet MLP (both stacks), outputs straight into w1s/w2s
    if (tid < 100){
        float s = b1a[tid];
        #pragma unroll
        for (int i = 0; i < 9; i++) s = fmaf(ka[i], w1a[i*100 + tid], s);
        hs[tid] = gelu_f(s);
    }
    __syncthreads();
    if (tid < 147){
        float s = b2a[tid];
        for (int k = 0; k < 100; k++) s = fmaf(hs[k], w2a[k*147 + tid], s);
        w1s[tid] = s;
    }
    __syncthreads();
    if (tid < 100){
        float s = b1b[tid];
        #pragma unroll
        for (int i = 0; i < 9; i++) s = fmaf(ka[i], w1b[i*100 + tid], s);
        hs[tid] = gelu_f(s);
    }
    __syncthreads();
    if (tid < 147){
        float s = b2b[tid];
        for (int k = 0; k < 100; k++) s = fmaf(hs[k], w2b[k*147 + tid], s);
        w2s[tid] = s;
    }
    // ct5 from c4 -> c5s (in U)
    {
        const float* ib = c4g + (size_t)b * (1089*32);
        float bb0 = b5[0], bb1 = b5[1];
        for (int p = tid; p < NN; p += 512){
            int oy = p / ND, ox = p % ND;
            float a0 = bb0, a1 = bb1;
            int nky, kyA[2], iyA[2];
            if ((oy & 1) == 0){ nky=2; kyA[0]=0; iyA[0]=oy/2+1; kyA[1]=2; iyA[1]=oy/2; }
            else              { nky=1; kyA[0]=1; iyA[0]=(oy+1)/2; kyA[1]=1; iyA[1]=0; }
            int nkx, kxA[2], ixA[2];
            if ((ox & 1) == 0){ nkx=2; kxA[0]=0; ixA[0]=ox/2+1; kxA[1]=2; ixA[1]=ox/2; }
            else              { nkx=1; kxA[0]=1; ixA[0]=(ox+1)/2; kxA[1]=1; ixA[1]=0; }
            for (int yi = 0; yi < nky; yi++)
            for (int xi = 0; xi < nkx; xi++){
                const float* ip = ib + ((size_t)iyA[yi]*33 + ixA[xi])*32;
                const float* wp = ws5b + (kyA[yi]*3 + kxA[xi])*64;
                #pragma unroll
                for (int g = 0; g < 8; g++){
                    F4 iv; iv.v = *(const float4*)(ip + 4*g);
                    #pragma unroll
                    for (int q = 0; q < 4; q++){
                        int ci = 4*g + q;
                        a0 = fmaf(iv.a[q], wp[ci*2],   a0);
                        a1 = fmaf(iv.a[q], wp[ci*2+1], a1);
                    }
                }
            }
            c5s[p]      = a0;
            c5s[NN + p] = a1;
        }
    }
    __syncthreads();
    // build vcs (rows 0..31, interleaved re/im pairs) + dvs
    {
        const float sc = 1.0f / 3969.0f;
        float4* vout = (float4*)vcs;
        for (int i = tid; i < 1024; i += 512){
            int ky = i >> 5, ct2 = i & 31;
            float4 o;
            #pragma unroll
            for (int j = 0; j < 2; j++){
                int kx = 2*ct2 + j;
                float re = 0.f, im = 0.f;
                if (kx <= 31){ int o2 = 2*(ky*ND + kx); re = c5s[o2]*sc; im = c5s[o2+1]*sc; }
                else if (kx <= 62){
                    int sy = (ND - ky) % ND, sx = ND - kx;
                    int o2 = 2*(sy*ND + sx); re = c5s[o2]*sc; im = -c5s[o2+1]*sc;
                }
                if (j == 0){ o.x = re; o.y = im; } else { o.z = re; o.w = im; }
            }
            vout[i] = o;
        }
        if (tid < 32){
            float2 d = {0.f, 0.f};
            if (tid >= 1){
                int iA = (ND - tid) * ND, iB = tid * ND;
                d.x = (c5s[2*iA]     - c5s[2*iB])     * sc;
                d.y = (c5s[2*iA + 1] + c5s[2*iB + 1]) * sc;
            }
            ((float2*)dvs)[tid] = d;
        }
    }
    __syncthreads();

    const int kt = tid >> 4, cg = tid & 15;

    for (int it = 0; it < 5; it++){
        // ---- zero union ----
        { float4 z = {0.f,0.f,0.f,0.f}; float4* U4 = (float4*)U;
          for (int i = tid; i < 2144; i += 512) U4[i] = z; }
        __syncthreads();
        // ---- residual -> rs (col c at idx c+3) ----
        for (int i = tid; i < NN; i += 512){
            int y = i / ND, xx = i % ND;
            float s = 0.f;
            #pragma unroll
            for (int dy = 0; dy < 3; dy++){
                int u = y + dy;
                #pragma unroll
                for (int dx = 0; dx < 3; dx++){
                    int v = xx + dx;
                    float p;
                    if (u == 64 || v == 64)    p = 1.0f;
                    else if (u == 0 || v == 0) p = 0.0f;
                    else                       p = xs[(u-1)*68 + (v-1)];
                    s = fmaf(p, ka[dy*3 + dx], s);
                }
            }
            rs[y*68 + 3 + xx] = fg[i] - s;
        }
        __syncthreads();
        // ---- smoother (r0 two-pass 7x7, proven no-spill) ----
        const bool act = tid < 504;
        const int y0 = tid >> 3, x0c = 8*(tid & 7);
        float acc2[8] = {};
        for (int c = 0; c < 3; c++){
            if (act){
                float a1[8] = {};
                for (int dy = 0; dy < 7; dy++){
                    int ry = y0 + dy - 3;
                    if (ry < 0 || ry >= 63) continue;
                    W16 w16;
                    const float4* rp = (const float4*)(rs + ry*68 + x0c);
                    w16.v[0]=rp[0]; w16.v[1]=rp[1]; w16.v[2]=rp[2]; w16.v[3]=rp[3];
                    #pragma unroll
                    for (int dx = 0; dx < 7; dx++){
                        float wv = w1s[c*49 + dy*7 + dx];
                        #pragma unroll
                        for (int t = 0; t < 8; t++) a1[t] = fmaf(wv, w16.a[t+dx], a1[t]);
                    }
                }
                int nw = 63 - x0c; if (nw > 8) nw = 8;
                for (int t = 0; t < nw; t++) tc[y0*68 + 3 + x0c + t] = a1[t];
            }
            __syncthreads();
            if (act){
                for (int dy = 0; dy < 7; dy++){
                    int ry = y0 + dy - 3;
                    if (ry < 0 || ry >= 63) continue;
                    W16 w16;
                    const float4* tp = (const float4*)(tc + ry*68 + x0c);
                    w16.v[0]=tp[0]; w16.v[1]=tp[1]; w16.v[2]=tp[2]; w16.v[3]=tp[3];
                    #pragma unroll
                    for (int dx = 0; dx < 7; dx++){
                        float wv = w2s[c*49 + dy*7 + dx];
                        #pragma unroll
                        for (int t = 0; t < 8; t++) acc2[t] = fmaf(wv, w16.a[t+dx], acc2[t]);
                    }
                }
            }
            __syncthreads();
        }
        if (act){
            int nw = 63 - x0c; if (nw > 8) nw = 8;
            for (int t = 0; t < nw; t++) xs[y0*68 + x0c + t] += acc2[t];
        }
        __syncthreads();
        // ---- residual of updated x -> rP ----
        for (int i = tid; i < 4096; i += 512){
            int y = i >> 6, xx = i & 63;
            float val = 0.f;
            if (y < 63 && xx < 63){
                float s = 0.f;
                #pragma unroll
                for (int dy = 0; dy < 3; dy++){
                    int u = y + dy;
                    #pragma unroll
                    for (int dx = 0; dx < 3; dx++){
                        int v = xx + dx;
                        float p;
                        if (u == 64 || v == 64)    p = 1.0f;
                        else if (u == 0 || v == 0) p = 0.0f;
                        else                       p = xs[(u-1)*68 + (v-1)];
                        s = fmaf(p, ka[dy*3 + dx], s);
                    }
                }
                val = fg[y*ND + xx] - s;
            }
            rP[i] = val;
        }
        __syncthreads();
        // ---- Phase A (F from global, float4 symmetry quads F[m][k]=F[k][m]) ----
        {
            float tr0=0.f,ti0=0.f,tr1=0.f,ti1=0.f,tr2=0.f,ti2=0.f,tr3=0.f,ti3=0.f;
            for (int mq = 0; mq < 16; mq++){
                F4 f4r, f4i;
                f4r.v = Fg4r[kt*16 + mq];
                f4i.v = Fg4i[kt*16 + mq];
                #pragma unroll
                for (int j = 0; j < 4; j++){
                    F4 rv; rv.v = rP4[(4*mq + j)*16 + cg];
                    float fr = f4r.a[j], fi = f4i.a[j];
                    tr0 = fmaf(fr, rv.a[0], tr0); ti0 = fmaf(fi, rv.a[0], ti0);
                    tr1 = fmaf(fr, rv.a[1], tr1); ti1 = fmaf(fi, rv.a[1], ti1);
                    tr2 = fmaf(fr, rv.a[2], tr2); ti2 = fmaf(fi, rv.a[2], ti2);
                    tr3 = fmaf(fr, rv.a[3], tr3); ti3 = fmaf(fi, rv.a[3], ti3);
                }
            }
            const int c0 = 4*cg;
            TtC[(c0+0)*32 + ((kt + c0 + 0) & 31)] = make_float2(tr0, ti0);
            TtC[(c0+1)*32 + ((kt + c0 + 1) & 31)] = make_float2(tr1, ti1);
            TtC[(c0+2)*32 + ((kt + c0 + 2) & 31)] = make_float2(tr2, ti2);
            TtC[(c0+3)*32 + ((kt + c0 + 3) & 31)] = make_float2(tr3, ti3);
        }
        __syncthreads();
        // ---- Phase B (F from global/L1 — off the LDS pipe) ----
        {
            float R0r=0.f,R0i=0.f,R1r=0.f,R1i=0.f,R2r=0.f,R2i=0.f,R3r=0.f,R3i=0.f;
            #pragma unroll 3
            for (int n = 0; n < 63; n++){
                float2 T = TtC[n*32 + ((kt + n) & 31)];
                F4 fr, fi;
                fr.v = Fg4r[n*16 + cg];
                fi.v = Fg4i[n*16 + cg];
                R0r = fmaf(T.x, fr.a[0], R0r); R0r = fmaf(-T.y, fi.a[0], R0r);
                R0i = fmaf(T.x, fi.a[0], R0i); R0i = fmaf( T.y, fr.a[0], R0i);
                R1r = fmaf(T.x, fr.a[1], R1r); R1r = fmaf(-T.y, fi.a[1], R1r);
                R1i = fmaf(T.x, fi.a[1], R1i); R1i = fmaf( T.y, fr.a[1], R1i);
                R2r = fmaf(T.x, fr.a[2], R2r); R2r = fmaf(-T.y, fi.a[2], R2r);
                R2i = fmaf(T.x, fi.a[2], R2i); R2i = fmaf( T.y, fr.a[2], R2i);
                R3r = fmaf(T.x, fr.a[3], R3r); R3r = fmaf(-T.y, fi.a[3], R3r);
                R3i = fmaf(T.x, fi.a[3], R3i); R3i = fmaf( T.y, fr.a[3], R3i);
            }
            if (cg == 0){
                float2 dv = ((const float2*)dvs)[kt];
                ds_r[kt] = R0r*dv.x + R0i*dv.y;
                ds_i[kt] = R0r*dv.y - R0i*dv.x;
            }
            float4 vA = vc4s[kt*32 + 2*cg];
            float4 vB = vc4s[kt*32 + 2*cg + 1];
            const int c0 = 4*cg, rot = kt;
            MC2[kt*64 + ((c0+0 + rot) & 63)] = make_float2(R0r*vA.x - R0i*vA.y, R0r*vA.y + R0i*vA.x);
            MC2[kt*64 + ((c0+1 + rot) & 63)] = make_float2(R1r*vA.z - R1i*vA.w, R1r*vA.w + R1i*vA.z);
            MC2[kt*64 + ((c0+2 + rot) & 63)] = make_float2(R2r*vB.x - R2i*vB.y, R2r*vB.y + R2i*vB.x);
            MC2[kt*64 + ((c0+3 + rot) & 63)] = make_float2(R3r*vB.z - R3i*vB.w, R3r*vB.w + R3i*vB.z);
        }
        __syncthreads();
        // ---- Phase D (F from global/L1) ----
        {
            float C0r=0.f,C0i=0.f,C1r=0.f,C1i=0.f,C2r=0.f,C2i=0.f,C3r=0.f,C3i=0.f;
            const int rot = kt;
            #pragma unroll 3
            for (int l = 0; l < 63; l++){
                float2 Mv = MC2[kt*64 + ((l + rot) & 63)];
                F4 fr, fi;
                fr.v = Fg4r[l*16 + cg];
                fi.v = Fg4i[l*16 + cg];
                C0r = fmaf(Mv.x, fr.a[0], C0r); C0r = fmaf( Mv.y, fi.a[0], C0r);
                C0i = fmaf(Mv.y, fr.a[0], C0i); C0i = fmaf(-Mv.x, fi.a[0], C0i);
                C1r = fmaf(Mv.x, fr.a[1], C1r); C1r = fmaf( Mv.y, fi.a[1], C1r);
                C1i = fmaf(Mv.y, fr.a[1], C1i); C1i = fmaf(-Mv.x, fi.a[1], C1i);
                C2r = fmaf(Mv.x, fr.a[2], C2r); C2r = fmaf( Mv.y, fi.a[2], C2r);
                C2i = fmaf(Mv.y, fr.a[2], C2i); C2i = fmaf(-Mv.x, fi.a[2], C2i);
                C3r = fmaf(Mv.x, fr.a[3], C3r); C3r = fmaf( Mv.y, fi.a[3], C3r);
                C3i = fmaf(Mv.y, fr.a[3], C3i); C3i = fmaf(-Mv.x, fi.a[3], C3i);
            }
            float sc2 = (kt == 0) ? 0.5f : 1.0f;
            CC4[kt*33 + 2*cg]     = make_float4(C0r*sc2, C0i*sc2, C1r*sc2, C1i*sc2);
            CC4[kt*33 + 2*cg + 1] = make_float4(C2r*sc2, C2i*sc2, C3r*sc2, C3i*sc2);
        }
        __syncthreads();
        // ---- Phase E: mirror-row pairing (rows pr and 63-pr share F magnitudes),
        // ---- F from global ----
        if (tid < 256){
            const int pr = tid >> 3, qb = tid & 7;
            float sr[8] = {}, si[8] = {};
            float er = 0.f, ei = 0.f;
            for (int nq = 0; nq < 8; nq++){
                F4 f4r, f4i;
                f4r.v = Fg4r[pr*16 + nq];
                f4i.v = Fg4i[pr*16 + nq];
                #pragma unroll
                for (int j = 0; j < 4; j++){
                    int n = 4*nq + j;
                    float fr = f4r.a[j], fi = f4i.a[j];
                    float4 cA = CC4[n*33 + qb];
                    float4 cB = CC4[n*33 + qb + 8];
                    float4 cC = CC4[n*33 + qb + 16];
                    float4 cD = CC4[n*33 + qb + 24];
                    sr[0]=fmaf(fr,cA.x,sr[0]); si[0]=fmaf(fi,cA.y,si[0]);
                    sr[1]=fmaf(fr,cA.z,sr[1]); si[1]=fmaf(fi,cA.w,si[1]);
                    sr[2]=fmaf(fr,cB.x,sr[2]); si[2]=fmaf(fi,cB.y,si[2]);
                    sr[3]=fmaf(fr,cB.z,sr[3]); si[3]=fmaf(fi,cB.w,si[3]);
                    sr[4]=fmaf(fr,cC.x,sr[4]); si[4]=fmaf(fi,cC.y,si[4]);
                    sr[5]=fmaf(fr,cC.z,sr[5]); si[5]=fmaf(fi,cC.w,si[5]);
                    sr[6]=fmaf(fr,cD.x,sr[6]); si[6]=fmaf(fi,cD.y,si[6]);
                    sr[7]=fmaf(fr,cD.z,sr[7]); si[7]=fmaf(fi,cD.w,si[7]);
                    er = fmaf(fr, ds_r[n], er); ei = fmaf(fi, ds_i[n], ei);
                }
            }
            {   // row pr: y = sr+si, e = er-ei
                float e0 = er - ei;
                float* xrow = xs + pr*68;
                float2* xp0 = (float2*)(xrow + 2*qb);
                float2* xp1 = (float2*)(xrow + 2*qb + 16);
                float2* xp2 = (float2*)(xrow + 2*qb + 32);
                float2* xp3 = (float2*)(xrow + 2*qb + 48);
                float2 v0=*xp0, v1=*xp1, v2=*xp2, v3=*xp3;
                v0.x += 2.f*(sr[0]+si[0]) + e0; v0.y += 2.f*(sr[1]+si[1]) + e0;
                v1.x += 2.f*(sr[2]+si[2]) + e0; v1.y += 2.f*(sr[3]+si[3]) + e0;
                v2.x += 2.f*(sr[4]+si[4]) + e0; v2.y += 2.f*(sr[5]+si[5]) + e0;
                v3.x += 2.f*(sr[6]+si[6]) + e0; v3.y += 2.f*(sr[7]+si[7]) + e0;
                *xp0=v0; *xp1=v1; *xp2=v2; *xp3=v3;
            }
            if (pr > 0){ // row 63-pr: fi -> -fi  =>  y = sr-si, e = er+ei
                float e1 = er + ei;
                float* xrow = xs + (63-pr)*68;
                float2* xp0 = (float2*)(xrow + 2*qb);
                float2* xp1 = (float2*)(xrow + 2*qb + 16);
                float2* xp2 = (float2*)(xrow + 2*qb + 32);
                float2* xp3 = (float2*)(xrow + 2*qb + 48);
                float2 v0=*xp0, v1=*xp1, v2=*xp2, v3=*xp3;
                v0.x += 2.f*(sr[0]-si[0]) + e1; v0.y += 2.f*(sr[1]-si[1]) + e1;
                v1.x += 2.f*(sr[2]-si[2]) + e1; v1.y += 2.f*(sr[3]-si[3]) + e1;
                v2.x += 2.f*(sr[4]-si[4]) + e1; v2.y += 2.f*(sr[5]-si[5]) + e1;
                v3.x += 2.f*(sr[6]-si[6]) + e1; v3.y += 2.f*(sr[7]-si[7]) + e1;
                *xp0=v0; *xp1=v1; *xp2=v2; *xp3=v3;
            }
        }
        __syncthreads();
    }
    // ---- final residual + norm ----
    float s = 0.f;
    for (int i = tid; i < NN; i += 512){
        int y = i / ND, xx = i % ND;
        float cv = 0.f;
        #pragma unroll
        for (int dy = 0; dy < 3; dy++){
            int u = y + dy;
            #pragma unroll
            for (int dx = 0; dx < 3; dx++){
                int v = xx + dx;
                float p;
                if (u == 64 || v == 64)    p = 1.0f;
                else if (u == 0 || v == 0) p = 0.0f;
                else                       p = xs[(u-1)*68 + (v-1)];
                cv = fmaf(p, ka[dy*3 + dx], cv);
            }
        }
        float r = fg[i] - cv;
        s = fmaf(r, r, s);
    }
    #pragma unroll
    for (int off = 32; off > 0; off >>= 1) s += __shfl_down(s, off, 64);
    int lane = tid & 63, w = tid >> 6;
    if (lane == 0) red[w] = s;
    __syncthreads();
    if (tid == 0){
        float t = 0.f;
        #pragma unroll
        for (int i = 0; i < 8; i++) t += red[i];
        atomicAdd(accg, t);
    }
}

__global__ void k_final(const float* __restrict__ acc, float* __restrict__ out){
    if (threadIdx.x == 0 && blockIdx.x == 0) out[0] = sqrtf(acc[0]) * (1.0f/256.0f);
}

// ---------------- host ------------------------------------------------------
extern "C" void kernel_launch(void* const* d_in, const int* in_sizes, int n_in,
                              void* d_out, int out_size, void* d_ws, size_t ws_size,
                              hipStream_t stream){
    const float* x0     = (const float*)d_in[0];
    const float* f      = (const float*)d_in[1];
    const float* kA     = (const float*)d_in[2];
    const float* fc1_w1 = (const float*)d_in[3];
    const float* fc1_b1 = (const float*)d_in[4];
    const float* fc1_w2 = (const float*)d_in[5];
    const float* fc1_b2 = (const float*)d_in[6];
    const float* fc2_w1 = (const float*)d_in[7];
    const float* fc2_b1 = (const float*)d_in[8];
    const float* fc2_w2 = (const float*)d_in[9];
    const float* fc2_b2 = (const float*)d_in[10];
    const float* ct1_w  = (const float*)d_in[11];
    const float* ct1_b  = (const float*)d_in[12];
    const float* ct2_w  = (const float*)d_in[13];
    const float* ct2_b  = (const float*)d_in[14];
    const float* ct3_w  = (const float*)d_in[15];
    const float* ct3_b  = (const float*)d_in[16];
    const float* ct4_w  = (const float*)d_in[17];
    const float* ct4_b  = (const float*)d_in[18];
    const float* ct5_w  = (const float*)d_in[19];
    const float* ct5_b  = (const float*)d_in[20];
    float* out = (float*)d_out;

    float* ws = (float*)d_ws;
    size_t off = 0;
    auto take = [&](size_t n){ float* p = ws + off; off += (n + 63) & ~(size_t)63; return p; };
    float* acc = take(64);
    float* Fr  = take(4096);
    float* Fi  = take(4096);
    float* c4  = take((size_t)NB*32*1089);
    (void)ws_size; (void)in_sizes; (void)n_in; (void)out_size;

    k_ct1234<<<NB, 512, 0, stream>>>(kA, ct1_w, ct2_w, ct3_w, ct4_w,
                                     ct1_b, ct2_b, ct3_b, ct4_b, c4, acc, Fr, Fi);
    k_solve<<<NB, 512, 0, stream>>>(x0, f, kA,
                                    fc1_w1, fc1_b1, fc1_w2, fc1_b2,
                                    fc2_w1, fc2_b1, fc2_w2, fc2_b2,
                                    ct5_w, ct5_b, Fr, Fi, c4, acc);
    k_final<<<1, 64, 0, stream>>>(acc, out);
}